// Round 2
// baseline (585.392 us; speedup 1.0000x reference)
//
#include <hip/hip_runtime.h>
#include <hip/hip_bf16.h>

typedef __attribute__((ext_vector_type(8))) short short8;
typedef __attribute__((ext_vector_type(4))) float f32x4;
typedef unsigned short u16;

#define DEV static __device__ __forceinline__

constexpr int Bsz = 4, Tn = 2048, Cn = 1024, Hn = 16, Dn = 64;

DEV u16 f2bf(float f) {
    union { float f; unsigned u; } v{f};
    unsigned u = v.u;
    unsigned r = (u + 0x7fffu + ((u >> 16) & 1u)) >> 16;
    return (u16)r;
}
DEV float bf2f(u16 u) {
    union { unsigned u; float f; } v;
    v.u = ((unsigned)u) << 16;
    return v.f;
}

DEV void gload_lds16(const void* g, void* l) {
    __builtin_amdgcn_global_load_lds((const __attribute__((address_space(1))) void*)g,
                                     (__attribute__((address_space(3))) void*)l, 16, 0, 0);
}

// ---------------- fp32 -> bf16 convert (vectorized) ----------------
__global__ void cvt_kernel(const float* __restrict__ in, u16* __restrict__ out, int n4) {
    int i = blockIdx.x * blockDim.x + threadIdx.x;
    int stride = gridDim.x * blockDim.x;
    for (; i < n4; i += stride) {
        float4 v = ((const float4*)in)[i];
        short4 o;
        o.x = (short)f2bf(v.x); o.y = (short)f2bf(v.y);
        o.z = (short)f2bf(v.z); o.w = (short)f2bf(v.w);
        ((short4*)out)[i] = o;
    }
}

// ---------------- RoPE trig tables [T][32] ----------------
__global__ void trig_kernel(float* __restrict__ cs, float* __restrict__ sn) {
    int idx = blockIdx.x * blockDim.x + threadIdx.x; // Tn*32
    int t = idx >> 5, i = idx & 31;
    double inv = pow(10000.0, -(double)i / 32.0);
    double a = (double)t * inv;
    cs[idx] = (float)cos(a);
    sn[idx] = (float)sin(a);
}

// ---------------- RoPE in place on [B,H,T,D] bf16 ----------------
__global__ void rope_kernel(u16* __restrict__ q, const float* __restrict__ cs,
                            const float* __restrict__ sn, int nrows) {
    int idx = blockIdx.x * blockDim.x + threadIdx.x;
    if (idx >= nrows * 32) return;
    int row = idx >> 5, i = idx & 31;
    int t = row & (Tn - 1); // row = (b*H+h)*T + t
    float c = cs[(t << 5) + i], s = sn[(t << 5) + i];
    u16* p = q + ((long)row << 6);
    float x1 = bf2f(p[i]), x2 = bf2f(p[i + 32]);
    p[i]      = f2bf(x1 * c - x2 * s);
    p[i + 32] = f2bf(x2 * c + x1 * s);
}

// ---------------- V transpose: [BH, T, 64] -> [BH, 64, T] ----------------
__global__ __launch_bounds__(256, 2) void transpose_v(const u16* __restrict__ in,
                                                      u16* __restrict__ out) {
    __shared__ u16 tile[64][68]; // stride 34 dwords: 2-way bank alias (free)
    int bh = blockIdx.y;
    long t0 = (long)blockIdx.x * 64;
    int tid = threadIdx.x;
#pragma unroll
    for (int c = 0; c < 2; c++) {
        int idx = c * 256 + tid;          // 0..511
        int r = idx >> 3, col = (idx & 7) << 3;
        *(short8*)&tile[r][col] = *(const short8*)&in[((long)bh * Tn + t0 + r) * 64 + col];
    }
    __syncthreads();
#pragma unroll
    for (int c = 0; c < 2; c++) {
        int idx = c * 256 + tid;
        int d = idx >> 3, tcol = (idx & 7) << 3;
        short8 v;
#pragma unroll
        for (int j = 0; j < 8; j++) v[j] = tile[tcol + j][d];
        *(short8*)&out[((long)bh * Dn + d) * Tn + t0 + tcol] = v;
    }
}

// ---------------- 128x128 bf16 GEMM, C = A * B^T ----------------
template <int MODE>
__global__ __launch_bounds__(256, 2) void gemm_bt(
    const u16* __restrict__ A,
    const u16* __restrict__ B0, const u16* __restrict__ B1, const u16* __restrict__ B2,
    void* __restrict__ O0, void* __restrict__ O1, void* __restrict__ O2,
    int M, int N, int K) {
    __shared__ u16 As[128 * 32];
    __shared__ u16 Bs[128 * 32];

    const u16* Bp = B0;
    void* Op = O0;
    if (MODE == 0) {
        if (blockIdx.z == 1) { Bp = B1; Op = O1; }
        else if (blockIdx.z == 2) { Bp = B2; Op = O2; }
    }
    int tid = threadIdx.x;
    int w = tid >> 6, lane = tid & 63;
    int lr = lane & 15, lg = lane >> 4;
    int wr = w >> 1, wc = w & 1;
    long brow = (long)blockIdx.x * 128, bcol = (long)blockIdx.y * 128;

    f32x4 acc[4][4] = {};
    const u16* Arow = A + brow * K;
    const u16* Brow = Bp + bcol * K;

    for (int k0 = 0; k0 < K; k0 += 32) {
        __syncthreads();
#pragma unroll
        for (int c = 0; c < 2; c++) {
            int idx = c * 256 + tid;
            int row = idx >> 2, col = (idx & 3) << 3;
            const u16* ga = Arow + (long)row * K + k0 + col;
            const u16* gb = Brow + (long)row * K + k0 + col;
            char* la = (char*)As + (size_t)(c * 256 + (tid & 192)) * 16;
            char* lb = (char*)Bs + (size_t)(c * 256 + (tid & 192)) * 16;
            gload_lds16(ga, la);
            gload_lds16(gb, lb);
        }
        __syncthreads();
        short8 a[4], b[4];
#pragma unroll
        for (int i = 0; i < 4; i++)
            a[i] = *(const short8*)&As[(64 * wr + 16 * i + lr) * 32 + lg * 8];
#pragma unroll
        for (int j = 0; j < 4; j++)
            b[j] = *(const short8*)&Bs[(64 * wc + 16 * j + lr) * 32 + lg * 8];
#pragma unroll
        for (int i = 0; i < 4; i++)
#pragma unroll
            for (int j = 0; j < 4; j++)
                acc[i][j] = __builtin_amdgcn_mfma_f32_16x16x32_bf16(a[i], b[j], acc[i][j], 0, 0, 0);
    }

#pragma unroll
    for (int i = 0; i < 4; i++)
#pragma unroll
        for (int j = 0; j < 4; j++)
#pragma unroll
            for (int jj = 0; jj < 4; jj++) {
                long gr = brow + 64 * wr + 16 * i + lg * 4 + jj;
                long gc = bcol + 64 * wc + 16 * j + lr;
                float v = acc[i][j][jj];
                if (MODE == 0) {
                    long b_ = gr >> 11, t_ = gr & 2047, h_ = gc >> 6, d_ = gc & 63;
                    ((u16*)Op)[(((b_ * Hn + h_) * Tn + t_) << 6) + d_] = f2bf(v);
                } else {
                    ((float*)Op)[gr * N + gc] = v;
                }
            }
}

// ---------------- flash attention, causal, D=64 ----------------
// Q,K: [B*H, T, 64] bf16 (rope applied). VT: [B*H, 64, T] bf16.
// Yb out: [B, T, C] bf16. Each wave owns 16 q-rows independently.
__global__ __launch_bounds__(256, 2) void attn_kernel(
    const u16* __restrict__ Q, const u16* __restrict__ K, const u16* __restrict__ VT,
    u16* __restrict__ Yb) {
    __shared__ u16 plds[4][16][68]; // stride 34 dwords: 2-way alias only

    int tid = threadIdx.x;
    int w = tid >> 6, lane = tid & 63;
    int lr = lane & 15, lg = lane >> 4;
    int qb = blockIdx.x * 4 + w;
    int q0 = qb * 16;
    long bh = blockIdx.y;
    const u16* Qp = Q + bh * Tn * Dn;
    const u16* Kp = K + bh * Tn * Dn;
    const u16* VTp = VT + bh * Dn * Tn;
    const float scale = 0.125f; // D^-0.5

    short8 aq[2];
#pragma unroll
    for (int ks = 0; ks < 2; ks++)
        aq[ks] = *(const short8*)&Qp[(long)(q0 + lr) * 64 + ks * 32 + lg * 8];

    f32x4 acc_o[4] = {};
    float m_[4], l_[4];
#pragma unroll
    for (int jj = 0; jj < 4; jj++) { m_[jj] = -1e30f; l_[jj] = 0.f; }

    int kv_end = q0 + 16;
    for (int kv0 = 0; kv0 < kv_end; kv0 += 64) {
        f32x4 s[4];
#pragma unroll
        for (int cblk = 0; cblk < 4; cblk++) {
            f32x4 sc = {};
#pragma unroll
            for (int ks = 0; ks < 2; ks++) {
                short8 bk = *(const short8*)&Kp[(long)(kv0 + cblk * 16 + lr) * 64 + ks * 32 + lg * 8];
                sc = __builtin_amdgcn_mfma_f32_16x16x32_bf16(aq[ks], bk, sc, 0, 0, 0);
            }
            int col = kv0 + cblk * 16 + lr;
#pragma unroll
            for (int jj = 0; jj < 4; jj++) {
                int row = q0 + lg * 4 + jj;
                float v = sc[jj] * scale;
                if (col > row) v = -1e30f;
                sc[jj] = v;
            }
            s[cblk] = sc;
        }
        // wave-parallel row max / exp / sum (16 lanes x 4 cblk per row)
#pragma unroll
        for (int jj = 0; jj < 4; jj++) {
            float v = fmaxf(fmaxf(s[0][jj], s[1][jj]), fmaxf(s[2][jj], s[3][jj]));
            v = fmaxf(v, __shfl_xor(v, 1));
            v = fmaxf(v, __shfl_xor(v, 2));
            v = fmaxf(v, __shfl_xor(v, 4));
            v = fmaxf(v, __shfl_xor(v, 8));
            float mn = fmaxf(m_[jj], v);
            float alpha = __expf(m_[jj] - mn);
            m_[jj] = mn;
            float sum = 0.f;
#pragma unroll
            for (int cblk = 0; cblk < 4; cblk++) {
                float p = __expf(s[cblk][jj] - mn);
                s[cblk][jj] = p;
                sum += p;
            }
            sum += __shfl_xor(sum, 1);
            sum += __shfl_xor(sum, 2);
            sum += __shfl_xor(sum, 4);
            sum += __shfl_xor(sum, 8);
            l_[jj] = l_[jj] * alpha + sum;
            acc_o[0][jj] *= alpha; acc_o[1][jj] *= alpha;
            acc_o[2][jj] *= alpha; acc_o[3][jj] *= alpha;
        }
        // P (C-layout) -> LDS -> A-frags (layout fix-up); same-wave, no barrier
#pragma unroll
        for (int cblk = 0; cblk < 4; cblk++)
#pragma unroll
            for (int jj = 0; jj < 4; jj++)
                plds[w][lg * 4 + jj][cblk * 16 + lr] = f2bf(s[cblk][jj]);
        short8 pa[2];
#pragma unroll
        for (int ks = 0; ks < 2; ks++)
            pa[ks] = *(const short8*)&plds[w][lr][ks * 32 + lg * 8];
        // PV: B-frag = coalesced short8 from VT rows (d-major)
#pragma unroll
        for (int ks = 0; ks < 2; ks++) {
#pragma unroll
            for (int dblk = 0; dblk < 4; dblk++) {
                short8 bv = *(const short8*)&VTp[(long)(dblk * 16 + lr) * Tn + kv0 + ks * 32 + lg * 8];
                acc_o[dblk] = __builtin_amdgcn_mfma_f32_16x16x32_bf16(pa[ks], bv, acc_o[dblk], 0, 0, 0);
            }
        }
    }
    // epilogue: y / l, write [B,T,C] bf16
    long b_ = bh / Hn, h_ = bh % Hn;
#pragma unroll
    for (int dblk = 0; dblk < 4; dblk++)
#pragma unroll
        for (int jj = 0; jj < 4; jj++) {
            int row = q0 + lg * 4 + jj;
            int d = dblk * 16 + lr;
            float v = acc_o[dblk][jj] / l_[jj];
            Yb[((b_ * Tn + row) * Cn) + h_ * 64 + d] = f2bf(v);
        }
}

extern "C" void kernel_launch(void* const* d_in, const int* in_sizes, int n_in,
                              void* d_out, int out_size, void* d_ws, size_t ws_size,
                              hipStream_t stream) {
    const float* x  = (const float*)d_in[0];
    const float* wq = (const float*)d_in[1];
    const float* wk = (const float*)d_in[2];
    const float* wv = (const float*)d_in[3];
    const float* wp = (const float*)d_in[4];

    char* ws = (char*)d_ws;
    size_t off = 0;
    auto alloc = [&](size_t bytes) {
        char* p = ws + off;
        off += (bytes + 255) & ~(size_t)255;
        return p;
    };
    const size_t BTC = (size_t)Bsz * Tn * Cn;
    u16* xb  = (u16*)alloc(BTC * 2);
    u16* wqb = (u16*)alloc((size_t)Cn * Cn * 2);
    u16* wkb = (u16*)alloc((size_t)Cn * Cn * 2);
    u16* wvb = (u16*)alloc((size_t)Cn * Cn * 2);
    u16* wpb = (u16*)alloc((size_t)Cn * Cn * 2);
    u16* qr  = (u16*)alloc(BTC * 2);
    u16* kr  = (u16*)alloc(BTC * 2);
    u16* vr  = (u16*)alloc(BTC * 2);
    u16* yb  = (u16*)alloc(BTC * 2);
    float* cs = (float*)alloc((size_t)Tn * 32 * 4);
    float* sn = (float*)alloc((size_t)Tn * 32 * 4);
    u16* vt  = xb; // alias: xb is dead after the QKV GEMM

    int M = Bsz * Tn; // 8192
    cvt_kernel<<<1024, 256, 0, stream>>>(x, xb, (int)(BTC / 4));
    cvt_kernel<<<256, 256, 0, stream>>>(wq, wqb, Cn * Cn / 4);
    cvt_kernel<<<256, 256, 0, stream>>>(wk, wkb, Cn * Cn / 4);
    cvt_kernel<<<256, 256, 0, stream>>>(wv, wvb, Cn * Cn / 4);
    cvt_kernel<<<256, 256, 0, stream>>>(wp, wpb, Cn * Cn / 4);
    trig_kernel<<<(Tn * 32) / 256, 256, 0, stream>>>(cs, sn);

    // QKV projections -> [B,H,T,D] bf16
    gemm_bt<0><<<dim3(M / 128, Cn / 128, 3), 256, 0, stream>>>(
        xb, wqb, wkb, wvb, qr, kr, vr, M, Cn, Cn);

    int nrows = Bsz * Hn * Tn; // 131072
    rope_kernel<<<(nrows * 32) / 256, 256, 0, stream>>>(qr, cs, sn, nrows);
    rope_kernel<<<(nrows * 32) / 256, 256, 0, stream>>>(kr, cs, sn, nrows);

    // V -> V^T [BH, D, T]  (xb reused as vt)
    transpose_v<<<dim3(Tn / 64, Bsz * Hn), 256, 0, stream>>>(vr, vt);

    attn_kernel<<<dim3(Tn / 64, Bsz * Hn), 256, 0, stream>>>(qr, kr, vt, yb);

    // output projection -> fp32 d_out
    gemm_bt<1><<<dim3(M / 128, Cn / 128, 1), 256, 0, stream>>>(
        yb, wpb, wpb, wpb, d_out, nullptr, nullptr, M, Cn, Cn);
}

// Round 3
// 274.773 us; speedup vs baseline: 2.1305x; 2.1305x over previous
//
#include <hip/hip_runtime.h>
#include <hip/hip_bf16.h>

typedef __attribute__((ext_vector_type(8))) short short8;
typedef __attribute__((ext_vector_type(4))) float f32x4;
typedef unsigned short u16;

#define DEV static __device__ __forceinline__

constexpr int Bsz = 4, Tn = 2048, Cn = 1024, Hn = 16, Dn = 64;
constexpr int TP = Tn + 32; // padded VT row stride: 4160B, breaks 4KB channel aliasing

DEV u16 f2bf(float f) {
    union { float f; unsigned u; } v{f};
    unsigned u = v.u;
    unsigned r = (u + 0x7fffu + ((u >> 16) & 1u)) >> 16;
    return (u16)r;
}
DEV float bf2f(u16 u) {
    union { unsigned u; float f; } v;
    v.u = ((unsigned)u) << 16;
    return v.f;
}

DEV void gload_lds16(const void* g, void* l) {
    __builtin_amdgcn_global_load_lds((const __attribute__((address_space(1))) void*)g,
                                     (__attribute__((address_space(3))) void*)l, 16, 0, 0);
}

// ---------------- fp32 -> bf16 convert (vectorized) ----------------
__global__ void cvt_kernel(const float* __restrict__ in, u16* __restrict__ out, int n4) {
    int i = blockIdx.x * blockDim.x + threadIdx.x;
    int stride = gridDim.x * blockDim.x;
    for (; i < n4; i += stride) {
        float4 v = ((const float4*)in)[i];
        short4 o;
        o.x = (short)f2bf(v.x); o.y = (short)f2bf(v.y);
        o.z = (short)f2bf(v.z); o.w = (short)f2bf(v.w);
        ((short4*)out)[i] = o;
    }
}

// ---------------- RoPE trig tables [T][32] ----------------
__global__ void trig_kernel(float* __restrict__ cs, float* __restrict__ sn) {
    int idx = blockIdx.x * blockDim.x + threadIdx.x; // Tn*32
    int t = idx >> 5, i = idx & 31;
    double inv = pow(10000.0, -(double)i / 32.0);
    double a = (double)t * inv;
    cs[idx] = (float)cos(a);
    sn[idx] = (float)sin(a);
}

// ---------------- RoPE in place on [B,H,T,D] bf16 ----------------
__global__ void rope_kernel(u16* __restrict__ q, const float* __restrict__ cs,
                            const float* __restrict__ sn, int nrows) {
    int idx = blockIdx.x * blockDim.x + threadIdx.x;
    if (idx >= nrows * 32) return;
    int row = idx >> 5, i = idx & 31;
    int t = row & (Tn - 1); // row = (b*H+h)*T + t
    float c = cs[(t << 5) + i], s = sn[(t << 5) + i];
    u16* p = q + ((long)row << 6);
    float x1 = bf2f(p[i]), x2 = bf2f(p[i + 32]);
    p[i]      = f2bf(x1 * c - x2 * s);
    p[i + 32] = f2bf(x2 * c + x1 * s);
}

// ---------------- V transpose: [BH, T, 64] -> [BH, 64, TP] ----------------
__global__ __launch_bounds__(256, 2) void transpose_v(const u16* __restrict__ in,
                                                      u16* __restrict__ out) {
    __shared__ u16 tile[64][68]; // stride 34 dwords: 2-way bank alias (free)
    int bh = blockIdx.y;
    long t0 = (long)blockIdx.x * 64;
    int tid = threadIdx.x;
#pragma unroll
    for (int c = 0; c < 2; c++) {
        int idx = c * 256 + tid;          // 0..511
        int r = idx >> 3, col = (idx & 7) << 3;
        *(short8*)&tile[r][col] = *(const short8*)&in[((long)bh * Tn + t0 + r) * 64 + col];
    }
    __syncthreads();
#pragma unroll
    for (int c = 0; c < 2; c++) {
        int idx = c * 256 + tid;
        int d = idx >> 3, tcol = (idx & 7) << 3;
        short8 v;
#pragma unroll
        for (int j = 0; j < 8; j++) v[j] = tile[tcol + j][d];
        *(short8*)&out[((long)bh * Dn + d) * TP + t0 + tcol] = v;
    }
}

// ---------------- 128x128 bf16 GEMM, C = A * B^T ----------------
template <int MODE>
__global__ __launch_bounds__(256, 2) void gemm_bt(
    const u16* __restrict__ A,
    const u16* __restrict__ B0, const u16* __restrict__ B1, const u16* __restrict__ B2,
    void* __restrict__ O0, void* __restrict__ O1, void* __restrict__ O2,
    int M, int N, int K) {
    __shared__ u16 As[128 * 32];
    __shared__ u16 Bs[128 * 32];

    const u16* Bp = B0;
    void* Op = O0;
    if (MODE == 0) {
        if (blockIdx.z == 1) { Bp = B1; Op = O1; }
        else if (blockIdx.z == 2) { Bp = B2; Op = O2; }
    }
    int tid = threadIdx.x;
    int w = tid >> 6, lane = tid & 63;
    int lr = lane & 15, lg = lane >> 4;
    int wr = w >> 1, wc = w & 1;
    long brow = (long)blockIdx.x * 128, bcol = (long)blockIdx.y * 128;

    f32x4 acc[4][4] = {};
    const u16* Arow = A + brow * K;
    const u16* Brow = Bp + bcol * K;

    for (int k0 = 0; k0 < K; k0 += 32) {
        __syncthreads();
#pragma unroll
        for (int c = 0; c < 2; c++) {
            int idx = c * 256 + tid;
            int row = idx >> 2, col = (idx & 3) << 3;
            const u16* ga = Arow + (long)row * K + k0 + col;
            const u16* gb = Brow + (long)row * K + k0 + col;
            char* la = (char*)As + (size_t)(c * 256 + (tid & 192)) * 16;
            char* lb = (char*)Bs + (size_t)(c * 256 + (tid & 192)) * 16;
            gload_lds16(ga, la);
            gload_lds16(gb, lb);
        }
        __syncthreads();
        short8 a[4], b[4];
#pragma unroll
        for (int i = 0; i < 4; i++)
            a[i] = *(const short8*)&As[(64 * wr + 16 * i + lr) * 32 + lg * 8];
#pragma unroll
        for (int j = 0; j < 4; j++)
            b[j] = *(const short8*)&Bs[(64 * wc + 16 * j + lr) * 32 + lg * 8];
#pragma unroll
        for (int i = 0; i < 4; i++)
#pragma unroll
            for (int j = 0; j < 4; j++)
                acc[i][j] = __builtin_amdgcn_mfma_f32_16x16x32_bf16(a[i], b[j], acc[i][j], 0, 0, 0);
    }

#pragma unroll
    for (int i = 0; i < 4; i++)
#pragma unroll
        for (int j = 0; j < 4; j++)
#pragma unroll
            for (int jj = 0; jj < 4; jj++) {
                long gr = brow + 64 * wr + 16 * i + lg * 4 + jj;
                long gc = bcol + 64 * wc + 16 * j + lr;
                float v = acc[i][j][jj];
                if (MODE == 0) {
                    long b_ = gr >> 11, t_ = gr & 2047, h_ = gc >> 6, d_ = gc & 63;
                    ((u16*)Op)[(((b_ * Hn + h_) * Tn + t_) << 6) + d_] = f2bf(v);
                } else {
                    ((float*)Op)[gr * N + gc] = v;
                }
            }
}

// ---------------- flash attention, causal, D=64 ----------------
// Q,K: [B*H, T, 64] bf16 (rope applied). VT: [B*H, 64, TP] bf16.
// Flat 512-block grid, XCD-swizzled: all 8 blocks of head bh satisfy gid%8==bh%8
// so each XCD's L2 caches 8 heads (~4.2 MB). Each wave processes the folded
// q-tile pair (i, 63-i): constant work per wave, no causal tail imbalance.
__global__ __launch_bounds__(256, 2) void attn_kernel(
    const u16* __restrict__ Q, const u16* __restrict__ K, const u16* __restrict__ VT,
    u16* __restrict__ Yb) {
    __shared__ u16 plds[4][32][68];

    int tid = threadIdx.x;
    int w = tid >> 6, lane = tid & 63;
    int lr = lane & 15, lg = lane >> 4;
    int gid = blockIdx.x;           // 0..511
    int xcd = gid & 7;
    int sl = gid >> 3;              // 0..63
    int bh = ((sl >> 3) << 3) + xcd; // 0..63
    int pairi = (sl & 7) * 4 + w;    // 0..31

    const u16* Qp = Q + (long)bh * Tn * Dn;
    const u16* Kp = K + (long)bh * Tn * Dn;
    const u16* VTp = VT + (long)bh * Dn * TP;
    const float scale = 0.125f; // D^-0.5
    long b_ = bh >> 4, h_ = bh & 15;

#pragma unroll
    for (int pass = 0; pass < 2; pass++) {
        int qt = pass == 0 ? pairi : 63 - pairi;
        int q0 = qt * 32;

        short8 aq[2][2];
#pragma unroll
        for (int qi = 0; qi < 2; qi++)
#pragma unroll
            for (int ks = 0; ks < 2; ks++)
                aq[qi][ks] = *(const short8*)&Qp[(long)(q0 + qi * 16 + lr) * 64 + ks * 32 + lg * 8];

        f32x4 acc[2][4] = {};
        float m_[2][4], l_[2][4];
#pragma unroll
        for (int qi = 0; qi < 2; qi++)
#pragma unroll
            for (int jj = 0; jj < 4; jj++) { m_[qi][jj] = -1e30f; l_[qi][jj] = 0.f; }

        int kv_end = q0 + 32;
        for (int kv0 = 0; kv0 < kv_end; kv0 += 64) {
            // ---- QK^T: K rows direct from global (L2-hot) ----
            f32x4 s[2][4];
#pragma unroll
            for (int cblk = 0; cblk < 4; cblk++) {
                short8 bk0 = *(const short8*)&Kp[(long)(kv0 + cblk * 16 + lr) * 64 + lg * 8];
                short8 bk1 = *(const short8*)&Kp[(long)(kv0 + cblk * 16 + lr) * 64 + 32 + lg * 8];
                int col = kv0 + cblk * 16 + lr;
#pragma unroll
                for (int qi = 0; qi < 2; qi++) {
                    f32x4 sc = {};
                    sc = __builtin_amdgcn_mfma_f32_16x16x32_bf16(aq[qi][0], bk0, sc, 0, 0, 0);
                    sc = __builtin_amdgcn_mfma_f32_16x16x32_bf16(aq[qi][1], bk1, sc, 0, 0, 0);
#pragma unroll
                    for (int jj = 0; jj < 4; jj++) {
                        int row = q0 + qi * 16 + lg * 4 + jj;
                        float v = sc[jj] * scale;
                        if (col > row) v = -1e30f;
                        sc[jj] = v;
                    }
                    s[qi][cblk] = sc;
                }
            }
            // ---- prefetch VT fragments (vmcnt drains under softmax) ----
            short8 bv[2][4];
#pragma unroll
            for (int ks = 0; ks < 2; ks++)
#pragma unroll
                for (int dblk = 0; dblk < 4; dblk++)
                    bv[ks][dblk] = *(const short8*)&VTp[(long)(dblk * 16 + lr) * TP + kv0 + ks * 32 + lg * 8];
            // ---- online softmax (wave-parallel, 16 lanes x 4 cblk per row) ----
#pragma unroll
            for (int qi = 0; qi < 2; qi++)
#pragma unroll
                for (int jj = 0; jj < 4; jj++) {
                    float v = fmaxf(fmaxf(s[qi][0][jj], s[qi][1][jj]),
                                    fmaxf(s[qi][2][jj], s[qi][3][jj]));
                    v = fmaxf(v, __shfl_xor(v, 1));
                    v = fmaxf(v, __shfl_xor(v, 2));
                    v = fmaxf(v, __shfl_xor(v, 4));
                    v = fmaxf(v, __shfl_xor(v, 8));
                    float mn = fmaxf(m_[qi][jj], v);
                    float alpha = __expf(m_[qi][jj] - mn);
                    m_[qi][jj] = mn;
                    float sum = 0.f;
#pragma unroll
                    for (int cblk = 0; cblk < 4; cblk++) {
                        float p = __expf(s[qi][cblk][jj] - mn);
                        s[qi][cblk][jj] = p;
                        sum += p;
                    }
                    sum += __shfl_xor(sum, 1);
                    sum += __shfl_xor(sum, 2);
                    sum += __shfl_xor(sum, 4);
                    sum += __shfl_xor(sum, 8);
                    l_[qi][jj] = l_[qi][jj] * alpha + sum;
#pragma unroll
                    for (int dblk = 0; dblk < 4; dblk++) acc[qi][dblk][jj] *= alpha;
                }
            // ---- P (C-layout) -> LDS -> A-frags; same-wave, no barrier ----
#pragma unroll
            for (int qi = 0; qi < 2; qi++)
#pragma unroll
                for (int cblk = 0; cblk < 4; cblk++)
#pragma unroll
                    for (int jj = 0; jj < 4; jj++)
                        plds[w][qi * 16 + lg * 4 + jj][cblk * 16 + lr] = f2bf(s[qi][cblk][jj]);
            short8 pa[2][2];
#pragma unroll
            for (int qi = 0; qi < 2; qi++)
#pragma unroll
                for (int ks = 0; ks < 2; ks++)
                    pa[qi][ks] = *(const short8*)&plds[w][qi * 16 + lr][ks * 32 + lg * 8];
            // ---- PV ----
#pragma unroll
            for (int ks = 0; ks < 2; ks++)
#pragma unroll
                for (int dblk = 0; dblk < 4; dblk++)
#pragma unroll
                    for (int qi = 0; qi < 2; qi++)
                        acc[qi][dblk] = __builtin_amdgcn_mfma_f32_16x16x32_bf16(
                            pa[qi][ks], bv[ks][dblk], acc[qi][dblk], 0, 0, 0);
        }
        // ---- epilogue: y / l -> [B,T,C] bf16 ----
#pragma unroll
        for (int qi = 0; qi < 2; qi++)
#pragma unroll
            for (int dblk = 0; dblk < 4; dblk++)
#pragma unroll
                for (int jj = 0; jj < 4; jj++) {
                    int row = q0 + qi * 16 + lg * 4 + jj;
                    int d = dblk * 16 + lr;
                    float v = acc[qi][dblk][jj] / l_[qi][jj];
                    Yb[((b_ * Tn + row) * Cn) + h_ * 64 + d] = f2bf(v);
                }
    }
}

extern "C" void kernel_launch(void* const* d_in, const int* in_sizes, int n_in,
                              void* d_out, int out_size, void* d_ws, size_t ws_size,
                              hipStream_t stream) {
    const float* x  = (const float*)d_in[0];
    const float* wq = (const float*)d_in[1];
    const float* wk = (const float*)d_in[2];
    const float* wv = (const float*)d_in[3];
    const float* wp = (const float*)d_in[4];

    char* ws = (char*)d_ws;
    size_t off = 0;
    auto alloc = [&](size_t bytes) {
        char* p = ws + off;
        off += (bytes + 255) & ~(size_t)255;
        return p;
    };
    const size_t BTC = (size_t)Bsz * Tn * Cn;
    u16* xb  = (u16*)alloc(BTC * 2);
    u16* wqb = (u16*)alloc((size_t)Cn * Cn * 2);
    u16* wkb = (u16*)alloc((size_t)Cn * Cn * 2);
    u16* wvb = (u16*)alloc((size_t)Cn * Cn * 2);
    u16* wpb = (u16*)alloc((size_t)Cn * Cn * 2);
    u16* qr  = (u16*)alloc(BTC * 2);
    u16* kr  = (u16*)alloc(BTC * 2);
    u16* vr  = (u16*)alloc(BTC * 2);
    u16* yb  = (u16*)alloc(BTC * 2);
    float* cs = (float*)alloc((size_t)Tn * 32 * 4);
    float* sn = (float*)alloc((size_t)Tn * 32 * 4);
    u16* vt  = xb; // alias: xb is dead after the QKV GEMM (17.0 MB < 32 MB)

    int M = Bsz * Tn; // 8192
    cvt_kernel<<<1024, 256, 0, stream>>>(x, xb, (int)(BTC / 4));
    cvt_kernel<<<256, 256, 0, stream>>>(wq, wqb, Cn * Cn / 4);
    cvt_kernel<<<256, 256, 0, stream>>>(wk, wkb, Cn * Cn / 4);
    cvt_kernel<<<256, 256, 0, stream>>>(wv, wvb, Cn * Cn / 4);
    cvt_kernel<<<256, 256, 0, stream>>>(wp, wpb, Cn * Cn / 4);
    trig_kernel<<<(Tn * 32) / 256, 256, 0, stream>>>(cs, sn);

    // QKV projections -> [B,H,T,D] bf16
    gemm_bt<0><<<dim3(M / 128, Cn / 128, 3), 256, 0, stream>>>(
        xb, wqb, wkb, wvb, qr, kr, vr, M, Cn, Cn);

    int nrows = Bsz * Hn * Tn; // 131072
    rope_kernel<<<(nrows * 32) / 256, 256, 0, stream>>>(qr, cs, sn, nrows);
    rope_kernel<<<(nrows * 32) / 256, 256, 0, stream>>>(kr, cs, sn, nrows);

    // V -> V^T [BH, D, TP]  (xb reused as vt)
    transpose_v<<<dim3(Tn / 64, Bsz * Hn), 256, 0, stream>>>(vr, vt);

    attn_kernel<<<dim3(512), 256, 0, stream>>>(qr, kr, vt, yb);

    // output projection -> fp32 d_out
    gemm_bt<1><<<dim3(M / 128, Cn / 128, 1), 256, 0, stream>>>(
        yb, wpb, wpb, wpb, d_out, nullptr, nullptr, M, Cn, Cn);
}

// Round 4
// 233.403 us; speedup vs baseline: 2.5081x; 1.1772x over previous
//
#include <hip/hip_runtime.h>
#include <hip/hip_bf16.h>

typedef __attribute__((ext_vector_type(8))) short short8;
typedef __attribute__((ext_vector_type(4))) float f32x4;
typedef unsigned short u16;

#define DEV static __device__ __forceinline__

constexpr int Bsz = 4, Tn = 2048, Cn = 1024, Hn = 16, Dn = 64;
constexpr int TP = Tn + 32;  // padded VT row stride: 4160B, breaks 4KB channel aliasing
constexpr int VROWS = 80;    // 64 d-rows + row64=ones (l-column) + 15 zero rows
// QK^T scale folded into Q at rope time: 0.125 * log2(e); softmax runs in exp2 domain.
#define QSCL 0.1803368801111204f

DEV u16 f2bf(float f) {  // round-to-nearest (ties away): 2 VALU
    union { float f; unsigned u; } v{f};
    return (u16)((v.u + 0x8000u) >> 16);
}
DEV float bf2f(u16 u) {
    union { unsigned u; float f; } v;
    v.u = ((unsigned)u) << 16;
    return v.f;
}

DEV void gload_lds16(const void* g, void* l) {
    __builtin_amdgcn_global_load_lds((const __attribute__((address_space(1))) void*)g,
                                     (__attribute__((address_space(3))) void*)l, 16, 0, 0);
}

// ---------------- fp32 -> bf16 convert (vectorized) ----------------
__global__ void cvt_kernel(const float* __restrict__ in, u16* __restrict__ out, int n4) {
    int i = blockIdx.x * blockDim.x + threadIdx.x;
    int stride = gridDim.x * blockDim.x;
    for (; i < n4; i += stride) {
        float4 v = ((const float4*)in)[i];
        short4 o;
        o.x = (short)f2bf(v.x); o.y = (short)f2bf(v.y);
        o.z = (short)f2bf(v.z); o.w = (short)f2bf(v.w);
        ((short4*)out)[i] = o;
    }
}

// ---------------- 4 weight matrices in one launch ----------------
__global__ void cvtw_kernel(const float* __restrict__ w0, const float* __restrict__ w1,
                            const float* __restrict__ w2, const float* __restrict__ w3,
                            u16* o0, u16* o1, u16* o2, u16* o3) {
    const float* src = blockIdx.y == 0 ? w0 : blockIdx.y == 1 ? w1 : blockIdx.y == 2 ? w2 : w3;
    u16* dst = blockIdx.y == 0 ? o0 : blockIdx.y == 1 ? o1 : blockIdx.y == 2 ? o2 : o3;
    int i = blockIdx.x * blockDim.x + threadIdx.x;
    float4 v = ((const float4*)src)[i];
    short4 o;
    o.x = (short)f2bf(v.x); o.y = (short)f2bf(v.y);
    o.z = (short)f2bf(v.z); o.w = (short)f2bf(v.w);
    ((short4*)dst)[i] = o;
}

// ---------------- RoPE trig tables [T][32] ----------------
__global__ void trig_kernel(float* __restrict__ cs, float* __restrict__ sn) {
    int idx = blockIdx.x * blockDim.x + threadIdx.x; // Tn*32
    int t = idx >> 5, i = idx & 31;
    double inv = pow(10000.0, -(double)i / 32.0);
    double a = (double)t * inv;
    cs[idx] = (float)cos(a);
    sn[idx] = (float)sin(a);
}

// ---------------- RoPE in place on Q and K [B,H,T,D] bf16 ----------------
// Q additionally scaled by QSCL (applied in f32 before the bf16 round).
__global__ void rope_kernel(u16* __restrict__ q, u16* __restrict__ k,
                            const float* __restrict__ cs, const float* __restrict__ sn) {
    int idx = blockIdx.x * blockDim.x + threadIdx.x;
    const int half = Bsz * Hn * Tn * 32;
    float scl = 1.0f;
    u16* p;
    if (idx >= half) { idx -= half; p = k; }
    else             { p = q; scl = QSCL; }
    int row = idx >> 5, i = idx & 31;
    int t = row & (Tn - 1);
    float c = cs[(t << 5) + i], s = sn[(t << 5) + i];
    u16* pr = p + ((long)row << 6);
    float x1 = bf2f(pr[i]), x2 = bf2f(pr[i + 32]);
    pr[i]      = f2bf((x1 * c - x2 * s) * scl);
    pr[i + 32] = f2bf((x2 * c + x1 * s) * scl);
}

// ---------------- V transpose: [BH, T, 64] -> [BH, VROWS, TP] ----------------
__global__ __launch_bounds__(256, 2) void transpose_v(const u16* __restrict__ in,
                                                      u16* __restrict__ out) {
    __shared__ u16 tile[64][68];
    int bh = blockIdx.y;
    long t0 = (long)blockIdx.x * 64;
    int tid = threadIdx.x;
#pragma unroll
    for (int c = 0; c < 2; c++) {
        int idx = c * 256 + tid;
        int r = idx >> 3, col = (idx & 7) << 3;
        *(short8*)&tile[r][col] = *(const short8*)&in[((long)bh * Tn + t0 + r) * 64 + col];
    }
    __syncthreads();
#pragma unroll
    for (int c = 0; c < 2; c++) {
        int idx = c * 256 + tid;
        int d = idx >> 3, tcol = (idx & 7) << 3;
        short8 v;
#pragma unroll
        for (int j = 0; j < 8; j++) v[j] = tile[tcol + j][d];
        *(short8*)&out[((long)bh * VROWS + d) * TP + t0 + tcol] = v;
    }
}

// rows 64..79 of each VT head: row 64 = 1.0 (l-column), rows 65..79 = 0
__global__ void fill_ones(u16* __restrict__ vt) {
    long idx = (long)blockIdx.x * 256 + threadIdx.x; // 64*16*TP total
    long bh = idx / (16 * TP);
    long rem = idx % (16 * TP);
    long r = rem / TP, t = rem % TP;
    vt[(bh * VROWS + 64 + r) * TP + t] = (r == 0) ? (u16)0x3f80 : (u16)0;
}

// ---------------- 128x128 bf16 GEMM, C = A * B^T ----------------
template <int MODE>
__global__ __launch_bounds__(256, 2) void gemm_bt(
    const u16* __restrict__ A,
    const u16* __restrict__ B0, const u16* __restrict__ B1, const u16* __restrict__ B2,
    void* __restrict__ O0, void* __restrict__ O1, void* __restrict__ O2,
    int M, int N, int K) {
    __shared__ u16 As[128 * 32];
    __shared__ u16 Bs[128 * 32];

    const u16* Bp = B0;
    void* Op = O0;
    if (MODE == 0) {
        if (blockIdx.z == 1) { Bp = B1; Op = O1; }
        else if (blockIdx.z == 2) { Bp = B2; Op = O2; }
    }
    int tid = threadIdx.x;
    int w = tid >> 6, lane = tid & 63;
    int lr = lane & 15, lg = lane >> 4;
    int wr = w >> 1, wc = w & 1;
    long brow = (long)blockIdx.x * 128, bcol = (long)blockIdx.y * 128;

    f32x4 acc[4][4] = {};
    const u16* Arow = A + brow * K;
    const u16* Brow = Bp + bcol * K;

    for (int k0 = 0; k0 < K; k0 += 32) {
        __syncthreads();
#pragma unroll
        for (int c = 0; c < 2; c++) {
            int idx = c * 256 + tid;
            int row = idx >> 2, col = (idx & 3) << 3;
            const u16* ga = Arow + (long)row * K + k0 + col;
            const u16* gb = Brow + (long)row * K + k0 + col;
            char* la = (char*)As + (size_t)(c * 256 + (tid & 192)) * 16;
            char* lb = (char*)Bs + (size_t)(c * 256 + (tid & 192)) * 16;
            gload_lds16(ga, la);
            gload_lds16(gb, lb);
        }
        __syncthreads();
        short8 a[4], b[4];
#pragma unroll
        for (int i = 0; i < 4; i++)
            a[i] = *(const short8*)&As[(64 * wr + 16 * i + lr) * 32 + lg * 8];
#pragma unroll
        for (int j = 0; j < 4; j++)
            b[j] = *(const short8*)&Bs[(64 * wc + 16 * j + lr) * 32 + lg * 8];
#pragma unroll
        for (int i = 0; i < 4; i++)
#pragma unroll
            for (int j = 0; j < 4; j++)
                acc[i][j] = __builtin_amdgcn_mfma_f32_16x16x32_bf16(a[i], b[j], acc[i][j], 0, 0, 0);
    }

#pragma unroll
    for (int i = 0; i < 4; i++)
#pragma unroll
        for (int j = 0; j < 4; j++)
#pragma unroll
            for (int jj = 0; jj < 4; jj++) {
                long gr = brow + 64 * wr + 16 * i + lg * 4 + jj;
                long gc = bcol + 64 * wc + 16 * j + lr;
                float v = acc[i][j][jj];
                if (MODE == 0) {
                    long b_ = gr >> 11, t_ = gr & 2047, h_ = gc >> 6, d_ = gc & 63;
                    ((u16*)Op)[(((b_ * Hn + h_) * Tn + t_) << 6) + d_] = f2bf(v);
                } else {
                    ((float*)Op)[gr * N + gc] = v;
                }
            }
}

// ---------------- flash attention, causal, D=64 ----------------
// Q pre-scaled by QSCL (softmax in exp2 domain). VT has an l-column at row 64.
// XCD-swizzled flat grid: each XCD's L2 caches 8 heads. Folded q-tile pairs
// (i, 63-i) per wave: constant work. Defer-max: common path has NO cross-lane ops.
__global__ __launch_bounds__(256, 2) void attn_kernel(
    const u16* __restrict__ Q, const u16* __restrict__ K, const u16* __restrict__ VT,
    u16* __restrict__ Yb) {
    __shared__ u16 plds[4][32][68];

    int tid = threadIdx.x;
    int w = tid >> 6, lane = tid & 63;
    int lr = lane & 15, lg = lane >> 4;
    int gid = blockIdx.x;            // 0..511
    int xcd = gid & 7;
    int sl = gid >> 3;               // 0..63
    int bh = ((sl >> 3) << 3) + xcd; // 0..63
    int pairi = (sl & 7) * 4 + w;    // 0..31

    const u16* Qp = Q + (long)bh * Tn * Dn;
    const u16* Kp = K + (long)bh * Tn * Dn;
    const u16* VTp = VT + (long)bh * VROWS * TP;
    long b_ = bh >> 4, h_ = bh & 15;

#pragma unroll
    for (int pass = 0; pass < 2; pass++) {
        int qt = pass == 0 ? pairi : 63 - pairi;
        int q0 = qt * 32;

        short8 aq[2][2];
#pragma unroll
        for (int qi = 0; qi < 2; qi++)
#pragma unroll
            for (int ks = 0; ks < 2; ks++)
                aq[qi][ks] = *(const short8*)&Qp[(long)(q0 + qi * 16 + lr) * 64 + ks * 32 + lg * 8];

        f32x4 acc[2][5] = {};        // [qi][dblk]; dblk 4 = l-column
        float m_[2][4];
#pragma unroll
        for (int qi = 0; qi < 2; qi++)
#pragma unroll
            for (int jj = 0; jj < 4; jj++) m_[qi][jj] = -1e30f;

        auto iter = [&](auto mc, int kv0) {
            constexpr bool MASKED = decltype(mc)::value;
            // ---- issue all 18 global loads up front ----
            short8 bk[4][2];
#pragma unroll
            for (int cblk = 0; cblk < 4; cblk++) {
                const u16* kb = &Kp[(long)(kv0 + cblk * 16 + lr) * 64 + lg * 8];
                bk[cblk][0] = *(const short8*)kb;
                bk[cblk][1] = *(const short8*)(kb + 32);
            }
            short8 bv[2][5];
#pragma unroll
            for (int ks = 0; ks < 2; ks++)
#pragma unroll
                for (int dblk = 0; dblk < 5; dblk++)
                    bv[ks][dblk] = *(const short8*)&VTp[(long)(dblk * 16 + lr) * TP + kv0 + ks * 32 + lg * 8];
            // ---- QK^T (scale pre-folded into Q) ----
            f32x4 s[2][4];
#pragma unroll
            for (int cblk = 0; cblk < 4; cblk++)
#pragma unroll
                for (int qi = 0; qi < 2; qi++) {
                    f32x4 sc = {};
                    sc = __builtin_amdgcn_mfma_f32_16x16x32_bf16(aq[qi][0], bk[cblk][0], sc, 0, 0, 0);
                    sc = __builtin_amdgcn_mfma_f32_16x16x32_bf16(aq[qi][1], bk[cblk][1], sc, 0, 0, 0);
                    if (MASKED) {
                        int col = kv0 + cblk * 16 + lr;
#pragma unroll
                        for (int jj = 0; jj < 4; jj++) {
                            int row = q0 + qi * 16 + lg * 4 + jj;
                            if (col > row) sc[jj] = -1e30f;
                        }
                    }
                    s[qi][cblk] = sc;
                }
            // ---- defer-max grow check (no cross-lane in common path) ----
            float pm[2][4];
            bool grow = false;
#pragma unroll
            for (int qi = 0; qi < 2; qi++)
#pragma unroll
                for (int jj = 0; jj < 4; jj++) {
                    pm[qi][jj] = fmaxf(fmaxf(s[qi][0][jj], s[qi][1][jj]),
                                       fmaxf(s[qi][2][jj], s[qi][3][jj]));
                    grow = grow || (pm[qi][jj] > m_[qi][jj] + 8.0f);
                }
            if (__any(grow)) {
#pragma unroll
                for (int qi = 0; qi < 2; qi++)
#pragma unroll
                    for (int jj = 0; jj < 4; jj++) {
                        float v = pm[qi][jj];
                        v = fmaxf(v, __shfl_xor(v, 1));
                        v = fmaxf(v, __shfl_xor(v, 2));
                        v = fmaxf(v, __shfl_xor(v, 4));
                        v = fmaxf(v, __shfl_xor(v, 8));
                        float mn = fmaxf(m_[qi][jj], v);
                        float alpha = __builtin_amdgcn_exp2f(m_[qi][jj] - mn);
                        m_[qi][jj] = mn;
#pragma unroll
                        for (int dblk = 0; dblk < 5; dblk++) acc[qi][dblk][jj] *= alpha;
                    }
            }
            // ---- P = exp2(s - m) -> LDS (C-layout -> A-frag fixup) ----
#pragma unroll
            for (int qi = 0; qi < 2; qi++)
#pragma unroll
                for (int cblk = 0; cblk < 4; cblk++)
#pragma unroll
                    for (int jj = 0; jj < 4; jj++)
                        plds[w][qi * 16 + lg * 4 + jj][cblk * 16 + lr] =
                            f2bf(__builtin_amdgcn_exp2f(s[qi][cblk][jj] - m_[qi][jj]));
            short8 pa[2][2];
#pragma unroll
            for (int qi = 0; qi < 2; qi++)
#pragma unroll
                for (int ks = 0; ks < 2; ks++)
                    pa[qi][ks] = *(const short8*)&plds[w][qi * 16 + lr][ks * 32 + lg * 8];
            // ---- PV (+l via ones-column, dblk=4) ----
#pragma unroll
            for (int ks = 0; ks < 2; ks++)
#pragma unroll
                for (int dblk = 0; dblk < 5; dblk++)
#pragma unroll
                    for (int qi = 0; qi < 2; qi++)
                        acc[qi][dblk] = __builtin_amdgcn_mfma_f32_16x16x32_bf16(
                            pa[qi][ks], bv[ks][dblk], acc[qi][dblk], 0, 0, 0);
        };

        int kv_end = q0 + 32;
        int last = ((kv_end - 1) >> 6) << 6;  // exactly one masked tail block
        for (int kv0 = 0; kv0 < last; kv0 += 64)
            iter(std::integral_constant<bool, false>{}, kv0);
        iter(std::integral_constant<bool, true>{}, last);

        // ---- epilogue: broadcast l from lr==0 lanes, y = acc/l ----
#pragma unroll
        for (int qi = 0; qi < 2; qi++)
#pragma unroll
            for (int jj = 0; jj < 4; jj++) {
                float l = __shfl(acc[qi][4][jj], lane & 48);
                float rl = 1.0f / l;
                int row = q0 + qi * 16 + lg * 4 + jj;
#pragma unroll
                for (int dblk = 0; dblk < 4; dblk++) {
                    int d = dblk * 16 + lr;
                    Yb[((b_ * Tn + row) * Cn) + h_ * 64 + d] = f2bf(acc[qi][dblk][jj] * rl);
                }
            }
    }
}

extern "C" void kernel_launch(void* const* d_in, const int* in_sizes, int n_in,
                              void* d_out, int out_size, void* d_ws, size_t ws_size,
                              hipStream_t stream) {
    const float* x  = (const float*)d_in[0];
    const float* wq = (const float*)d_in[1];
    const float* wk = (const float*)d_in[2];
    const float* wv = (const float*)d_in[3];
    const float* wp = (const float*)d_in[4];

    char* ws = (char*)d_ws;
    size_t off = 0;
    auto alloc = [&](size_t bytes) {
        char* p = ws + off;
        off += (bytes + 255) & ~(size_t)255;
        return p;
    };
    const size_t BTC = (size_t)Bsz * Tn * Cn;
    u16* xb  = (u16*)alloc(BTC * 2);
    u16* wqb = (u16*)alloc((size_t)Cn * Cn * 2);
    u16* wkb = (u16*)alloc((size_t)Cn * Cn * 2);
    u16* wvb = (u16*)alloc((size_t)Cn * Cn * 2);
    u16* wpb = (u16*)alloc((size_t)Cn * Cn * 2);
    u16* qr  = (u16*)alloc(BTC * 2);
    u16* kr  = (u16*)alloc(BTC * 2);
    u16* vr  = (u16*)alloc(BTC * 2);
    u16* yb  = (u16*)alloc(BTC * 2);
    float* cs = (float*)alloc((size_t)Tn * 32 * 4);
    float* sn = (float*)alloc((size_t)Tn * 32 * 4);
    // vt aliases xb (dead after QKV GEMM) and spills into wqb/wkb/wvb (also dead
    // by transpose time): 64*80*TP*2 = 21.3 MB < xb+wqb+wkb+wvb = 23.07 MB; wpb safe.
    u16* vt  = xb;

    int M = Bsz * Tn; // 8192
    cvt_kernel<<<1024, 256, 0, stream>>>(x, xb, (int)(BTC / 4));
    cvtw_kernel<<<dim3(Cn * Cn / 4 / 256, 4), 256, 0, stream>>>(
        wq, wk, wv, wp, wqb, wkb, wvb, wpb);
    trig_kernel<<<(Tn * 32) / 256, 256, 0, stream>>>(cs, sn);

    // QKV projections -> [B,H,T,D] bf16
    gemm_bt<0><<<dim3(M / 128, Cn / 128, 3), 256, 0, stream>>>(
        xb, wqb, wkb, wvb, qr, kr, vr, M, Cn, Cn);

    // RoPE on Q (scaled by QSCL) and K, one launch
    int nrows = Bsz * Hn * Tn; // 131072
    rope_kernel<<<(2 * nrows * 32) / 256, 256, 0, stream>>>(qr, kr, cs, sn);

    // V -> V^T [BH, VROWS, TP] + l-column
    transpose_v<<<dim3(Tn / 64, Bsz * Hn), 256, 0, stream>>>(vr, vt);
    fill_ones<<<(64 * 16 * TP) / 256, 256, 0, stream>>>(vt);

    attn_kernel<<<dim3(512), 256, 0, stream>>>(qr, kr, vt, yb);

    // output projection -> fp32 d_out
    gemm_bt<1><<<dim3(M / 128, Cn / 128, 1), 256, 0, stream>>>(
        yb, wpb, wpb, wpb, d_out, nullptr, nullptr, M, Cn, Cn);
}